// Round 9
// baseline (1110.335 us; speedup 1.0000x reference)
//
#include <hip/hip_runtime.h>
#include <hip/hip_bf16.h>

typedef __hip_bfloat16 bf16;
typedef unsigned char u8;
typedef long long i64;
typedef __attribute__((ext_vector_type(8))) __bf16 bf16x8;
typedef __attribute__((ext_vector_type(4))) float f32x4;
typedef __attribute__((ext_vector_type(2))) i64 i64x2;

#define B_   64
#define NPG_ 20
#define H_   512
#define TD_  256
#define NF_  128
#define NL_  6
#define A_   100
#define N_   (B_ * NPG_)            // 1280
#define E_   (B_ * NPG_ * (NPG_-1)) // 24320
#define EIN_ 2313
#define KF8_ 896                     // 768 femb + 9 geo + pad, padded to 7x128

__device__ __forceinline__ float bf2f(bf16 x) { return __bfloat162float(x); }
__device__ __forceinline__ bf16  f2bf(float x) { return __float2bfloat16(x); }
__device__ __forceinline__ float siluf(float x) { return x / (1.0f + expf(-x)); }
__device__ __forceinline__ float ldf(const void* p, size_t i, int isb) {
    return isb ? bf2f(((const bf16*)p)[i]) : ((const float*)p)[i];
}
// k-order permutation within a 128-byte superblock: orig [kk:2][lq:2][j:3] -> [lq:2][kk:2][j:3]
// so each lane's two adjacent MFMA fragments are contiguous 16B.
__device__ __forceinline__ int perm_k(int o) {
    return (o & ~127) | (((o >> 3) & 3) << 5) | (((o >> 5) & 3) << 3) | (o & 7);
}
// manual float -> OCP e4m3fn (round-nearest-even)
__device__ __forceinline__ u8 f2f8(float f) {
    unsigned s = (__float_as_uint(f) >> 24) & 0x80;
    float a = fabsf(f);
    if (!(a == a)) return (u8)0x7F;
    if (a == 0.0f) return (u8)s;
    if (a >= 448.0f) return (u8)(s | 0x7E);
    int e; float m = frexpf(a, &e);
    int ef = e + 6;
    unsigned code;
    if (ef >= 1) {
        int mant = (int)rintf(m * 16.0f) - 8;
        if (mant == 8) { mant = 0; ef++; }
        if (ef > 15) return (u8)(s | 0x7E);
        code = ((unsigned)ef << 3) | (unsigned)mant;
    } else {
        int mant = (int)rintf(ldexpf(a, 9));
        code = (mant >= 8) ? (1u<<3) : (unsigned)mant;
    }
    return (u8)(s | code);
}
__device__ __forceinline__ void async_cp16(const void* src, void* dst) {
    __builtin_amdgcn_global_load_lds(
        (const __attribute__((address_space(1))) unsigned int*)src,
        (__attribute__((address_space(3))) unsigned int*)dst,
        16, 0, 0);
}

// ---------------------------------------------------------------- dtype detect on t (uniform [0,1))
__global__ void detect_dtype(const unsigned int* __restrict__ tw, int* __restrict__ flag) {
    if (threadIdx.x != 0) return;
    int cnt = 0;
    for (int i = 0; i < 32; i++) {
        unsigned b1 = (tw[i] >> 8) & 0xFF;
        if (b1 >= 0x20 && b1 < 0x40) cnt++;
    }
    *flag = (cnt >= 16) ? 1 : 0;
}

__global__ void ws_sentinel(bf16* out) { if (threadIdx.x == 0) out[0] = f2bf(1000.0f); }

// ---------------------------------------------------------------- prep: lattice -> ltl (B,3,3)
__global__ void prep_graph(const void* __restrict__ latp, float* __restrict__ ltl,
                           const int* __restrict__ flag) {
    int b = threadIdx.x;
    if (b >= B_) return;
    int isb = *flag;
    const float LM[3] = {1.575442910194397f, 1.7017393112182617f, 1.9781638383865356f};
    const float LS[3] = {0.24437622725963593f, 0.26526379585266113f, 0.3535512685775757f};
    float lp[6];
    for (int i = 0; i < 6; i++) lp[i] = ldf(latp, b*6 + i, isb);
    float len[3], c[3], s[3];
    for (int i = 0; i < 3; i++) len[i] = expf(lp[i] * LS[i] + LM[i]);
    for (int i = 0; i < 3; i++) {
        float sig = 1.0f / (1.0f + expf(-lp[3+i]));
        float deg = 59.9f + 60.2f * sig;
        float a = deg * 0.017453292519943295f;
        c[i] = cosf(a); s[i] = sinf(a);
    }
    float val = (c[0]*c[1] - c[2]) / (s[0]*s[1]);
    val = fminf(1.0f, fmaxf(-1.0f, val));
    float gs = acosf(val);
    float L[3][3];
    L[0][0] = len[0]*s[1]; L[0][1] = 0.0f;               L[0][2] = len[0]*c[1];
    L[1][0] = -len[1]*s[0]*cosf(gs); L[1][1] = len[1]*s[0]*sinf(gs); L[1][2] = len[1]*c[0];
    L[2][0] = 0.0f; L[2][1] = 0.0f; L[2][2] = len[2];
    for (int i = 0; i < 3; i++)
        for (int k = 0; k < 3; k++)
            ltl[b*9 + i*3 + k] = L[i][0]*L[k][0] + L[i][1]*L[k][1] + L[i][2]*L[k][2];
}

// ---------------------------------------------------------------- prep: q[j] = sum_d W_time[d]*W_latent[512+d][j]
__global__ __launch_bounds__(512) void prep_q(const void* __restrict__ W_time,
                                              const void* __restrict__ W_latent,
                                              float* __restrict__ q,
                                              const int* __restrict__ flag) {
    int j = threadIdx.x;
    int isb = *flag;
    float s0 = 0.0f, s1 = 0.0f, s2 = 0.0f, s3 = 0.0f;
    for (int d = 0; d < TD_; d += 4) {
        s0 += ldf(W_time, d+0, isb) * ldf(W_latent, (size_t)(H_ + d+0)*H_ + j, isb);
        s1 += ldf(W_time, d+1, isb) * ldf(W_latent, (size_t)(H_ + d+1)*H_ + j, isb);
        s2 += ldf(W_time, d+2, isb) * ldf(W_latent, (size_t)(H_ + d+2)*H_ + j, isb);
        s3 += ldf(W_time, d+3, isb) * ldf(W_latent, (size_t)(H_ + d+3)*H_ + j, isb);
    }
    q[j] = (s0 + s1) + (s2 + s3);
}

// ---------------------------------------------------------------- gather A rows for PQ gemm (7 slots of 128x512)
__global__ __launch_bounds__(256) void pq_gather(const void* __restrict__ W_node,
                                                 const void* __restrict__ W_numatom,
                                                 bf16* __restrict__ PQa,
                                                 const int* __restrict__ flag) {
    int z = blockIdx.x, ch = blockIdx.y;
    int isb = *flag;
    int base = ch * 4096;
    for (int idx = base + threadIdx.x; idx < base + 4096; idx += 256) {
        int r = idx >> 9, c = idx & 511;
        float v = 0.0f;
        if (r < A_) {
            if (z == 0) v = ldf(W_node, (size_t)r*512 + c, isb);
            else        v = ldf(W_numatom, ((size_t)(z-1)*A_ + r)*512 + c, isb);
        }
        PQa[(size_t)z*65536 + idx] = f2bf(v);
    }
}

// ---------------------------------------------------------------- transpose for PQ Bt (7 slots of 512x512)
__global__ __launch_bounds__(256) void transpose_pq(const void* __restrict__ W_latent,
                                                    const void* __restrict__ We1,
                                                    bf16* __restrict__ PQbt,
                                                    const int* __restrict__ flag) {
    __shared__ bf16 tile[32][33];
    int z = blockIdx.z;
    int isb = *flag;
    const void* src = (z == 0) ? W_latent : We1;
    size_t off = (z == 0) ? 0 : ((size_t)(z-1)*EIN_ + 1801)*512;
    bf16* dst = PQbt + (size_t)z*512*512;
    int r0 = blockIdx.y * 32, c0 = blockIdx.x * 32;
    #pragma unroll
    for (int i = 0; i < 32; i += 8)
        tile[threadIdx.y + i][threadIdx.x] =
            f2bf(ldf(src, off + (size_t)(r0 + threadIdx.y + i)*512 + c0 + threadIdx.x, isb));
    __syncthreads();
    #pragma unroll
    for (int i = 0; i < 32; i += 8)
        dst[(size_t)(c0 + threadIdx.y + i)*512 + r0 + threadIdx.x] = tile[threadIdx.x][threadIdx.y + i];
}

// ---------------------------------------------------------------- weight transpose; z = lz*6 + which
// which 2 (Wtf8, stride KF8_) and 3 (Wte28, stride 512) write fp8 with perm_k; others bf16
__global__ __launch_bounds__(256) void transpose_layer(
    const void* __restrict__ We1p, const void* __restrict__ We2p,
    const void* __restrict__ Wn1p, const void* __restrict__ Wn2p, size_t l0, int allmode,
    bf16* __restrict__ WtAB, u8* __restrict__ Wtf8, u8* __restrict__ Wte28,
    bf16* __restrict__ Wtn1, bf16* __restrict__ Wtn2,
    const int* __restrict__ flag) {
    __shared__ bf16 tile[32][33];
    int which = blockIdx.z % 6;
    size_t lz = blockIdx.z / 6;
    size_t l = l0 + lz, lw = allmode ? lz : 0;
    int isb = *flag;
    const void* src; size_t off; bf16* dst = nullptr; u8* d8 = nullptr; int R; int ldd;
    switch (which) {
        case 0:  src = We1p; off = (l*EIN_ + 3)*512;    dst = WtAB + lw*512*1024;            R = 512;  ldd = 512;  break;
        case 1:  src = We1p; off = (l*EIN_ + 515)*512;  dst = WtAB + lw*512*1024 + 512*512;  R = 512;  ldd = 512;  break;
        case 2:  src = We1p; off = (l*EIN_ + 1033)*512; d8 = Wtf8 + lw*(size_t)512*KF8_;     R = 768;  ldd = KF8_; break;
        case 3:  src = We2p; off = l*512*512;           d8 = Wte28 + lw*(size_t)512*512;     R = 512;  ldd = 512;  break;
        case 4:  src = Wn1p; off = l*1024*512;          dst = Wtn1 + lw*512*1024;            R = 1024; ldd = 1024; break;
        default: src = Wn2p; off = l*512*512;           dst = Wtn2 + lw*512*512;             R = 512;  ldd = 512; break;
    }
    int r0 = blockIdx.y * 32, c0 = blockIdx.x * 32;
    if (r0 >= R) return;
    #pragma unroll
    for (int i = 0; i < 32; i += 8)
        tile[threadIdx.y + i][threadIdx.x] =
            f2bf(ldf(src, off + (size_t)(r0 + threadIdx.y + i)*512 + c0 + threadIdx.x, isb));
    __syncthreads();
    if (which == 2 || which == 3) {
        int kp = perm_k(r0 + threadIdx.x);
        #pragma unroll
        for (int i = 0; i < 32; i += 8)
            d8[(size_t)(c0 + threadIdx.y + i)*ldd + kp] =
                f2f8(bf2f(tile[threadIdx.x][threadIdx.y + i]));
    } else {
        #pragma unroll
        for (int i = 0; i < 32; i += 8)
            dst[(size_t)(c0 + threadIdx.y + i)*ldd + r0 + threadIdx.x] = tile[threadIdx.x][threadIdx.y + i];
    }
}

// ---------------------------------------------------------------- Wtf8 tail cols 768..895: 9 geometry rows of We1, rest 0
__global__ __launch_bounds__(512) void wtf_tail(const void* __restrict__ We1, size_t l0, int allmode,
                                                u8* __restrict__ Wtf8,
                                                const int* __restrict__ flag) {
    size_t lz = blockIdx.x;
    size_t l = l0 + lz, lw = allmode ? lz : 0;
    int n = threadIdx.x;
    int isb = *flag;
    const int rows[9] = {0, 1, 2, 1027, 1028, 1029, 1030, 1031, 1032};
    u8* d8 = Wtf8 + lw*(size_t)512*KF8_;
    #pragma unroll
    for (int j = 0; j < 128; j++) {
        float v = (j < 9) ? ldf(We1, (l*EIN_ + rows[j])*512 + n, isb) : 0.0f;
        d8[(size_t)n*KF8_ + perm_k(768 + j)] = f2f8(v);
    }
}

// ---------------------------------------------------------------- cbias[l][g][j] = be1[l][j] + Qc[1+l][na_g][j]
__global__ __launch_bounds__(512) void cbias_prep(const bf16* __restrict__ PQc,
                                                  const void* __restrict__ be1,
                                                  const int* __restrict__ num_atoms,
                                                  float* __restrict__ cbias,
                                                  const int* __restrict__ flag) {
    int l = blockIdx.x, g = blockIdx.y, j = threadIdx.x;
    int isb = *flag;
    int na = num_atoms[g] - 1;
    float qv = (na >= 0 && na < A_) ? bf2f(PQc[(size_t)(1+l)*65536 + (size_t)na*512 + j]) : 0.0f;
    cbias[((size_t)l*B_ + g)*512 + j] = ldf(be1, l*512 + j, isb) + qv;
}

// ---------------------------------------------------------------- node embed
__global__ __launch_bounds__(512) void node_embed_fast(const bf16* __restrict__ P,
                                                       const float* __restrict__ q,
                                                       const void* __restrict__ t,
                                                       const int* __restrict__ atom_types,
                                                       const int* __restrict__ node2graph,
                                                       float* __restrict__ h,
                                                       const int* __restrict__ flag) {
    int i = blockIdx.x, j = threadIdx.x;
    int isb = *flag;
    int at = atom_types[i] - 1; if (at < 0) at = 0;
    float pv = (at < A_) ? bf2f(P[(size_t)at*512 + j]) : 0.0f;
    float tv = ldf(t, node2graph[i], isb);
    h[(size_t)i*H_ + j] = pv + tv * q[j];
}

// ---------------------------------------------------------------- edge prep: femb8(E x 896 fp8, k-permuted) + edat
__global__ __launch_bounds__(384) void edge_prep(const void* __restrict__ frac,
                                                 const int* __restrict__ edge_index,
                                                 const int* __restrict__ e2g,
                                                 const void* __restrict__ latp,
                                                 const float* __restrict__ ltl,
                                                 int* __restrict__ edat,
                                                 u8* __restrict__ femb8,
                                                 const int* __restrict__ flag) {
    const float TWO_PI_F = 6.283185307179586f;
    int e = blockIdx.x;
    int isb = *flag;
    int src = edge_index[e], dst = edge_index[E_ + e];
    int tid = threadIdx.x;
    int d = tid >> 7, k = tid & 127;
    float x = ldf(frac, src*3 + d, isb), y = ldf(frac, dst*3 + d, isb);
    float diff = y - x;
    float fd = diff - rintf(diff);
    float sv, cv;
    sincosf(fd * (TWO_PI_F * (float)k), &sv, &cv);
    femb8[(size_t)e*KF8_ + perm_k(d*NF_ + k)]       = f2f8(sv);
    femb8[(size_t)e*KF8_ + perm_k(384 + d*NF_ + k)] = f2f8(cv);
    if (tid < 128) {
        int g = e2g[e];
        float v = 0.0f;
        if (tid < 3) {
            float f3[3];
            for (int dd = 0; dd < 3; dd++) {
                float df = ldf(frac, dst*3 + dd, isb) - ldf(frac, src*3 + dd, isb);
                f3[dd] = df - rintf(df);
            }
            float dots[3];
            for (int i = 0; i < 3; i++)
                dots[i] = ltl[g*9 + i*3 + 0]*f3[0] + ltl[g*9 + i*3 + 1]*f3[1] + ltl[g*9 + i*3 + 2]*f3[2];
            float nrm = sqrtf(dots[0]*dots[0] + dots[1]*dots[1] + dots[2]*dots[2]);
            v = dots[tid] / (nrm + 1e-12f);
        } else if (tid < 9) {
            v = ldf(latp, g*6 + tid - 3, isb);
        }
        femb8[(size_t)e*KF8_ + perm_k(768 + tid)] = f2f8(v);
        if (tid == 0) {
            edat[e*4 + 0] = src;
            edat[e*4 + 1] = dst;
            edat[e*4 + 2] = g;
            edat[e*4 + 3] = 0;
        }
    }
}

// ---------------------------------------------------------------- layernorm over H=512 -> cat[:, :512] (stride 1024)
__device__ __forceinline__ float block_sum_256(float v, float* red) {
    for (int o = 32; o; o >>= 1) v += __shfl_down(v, o);
    int w = threadIdx.x >> 6, lane = threadIdx.x & 63;
    if (lane == 0) red[w] = v;
    __syncthreads();
    float s = red[0] + red[1] + red[2] + red[3];
    __syncthreads();
    return s;
}

__global__ __launch_bounds__(256) void ln_kernel(const float* __restrict__ x,
                                                 const void* __restrict__ gamma,
                                                 const void* __restrict__ beta, size_t goff,
                                                 bf16* __restrict__ cat,
                                                 const int* __restrict__ flag) {
    __shared__ float red[4];
    size_t n = blockIdx.x;
    int tid = threadIdx.x;
    int isb = *flag;
    const float* xr = x + n*H_;
    float v0 = xr[tid], v1 = xr[tid + 256];
    float mu = block_sum_256(v0 + v1, red) * (1.0f/512.0f);
    float d0 = v0 - mu, d1 = v1 - mu;
    float var = block_sum_256(d0*d0 + d1*d1, red) * (1.0f/512.0f);
    float rs = 1.0f / sqrtf(var + 1e-5f);
    cat[n*1024 + tid]       = f2bf(d0*rs*ldf(gamma, goff + tid, isb)       + ldf(beta, goff + tid, isb));
    cat[n*1024 + 256 + tid] = f2bf(d1*rs*ldf(gamma, goff + tid + 256, isb) + ldf(beta, goff + tid + 256, isb));
}

// ---------------------------------------------------------------- bf16 MFMA GEMM (EPI 0/1/2), BK=64, async+XOR swizzle
template<int EPI, int TM>
__global__ __launch_bounds__(256) void gemm_bt(
        const bf16* __restrict__ A, int lda,
        const bf16* __restrict__ Bt,
        const void* __restrict__ bias, size_t boff,
        bf16* __restrict__ Cb, float* __restrict__ Cf,
        int K, int N,
        size_t zsA, size_t zsB, size_t zsC,
        const int* __restrict__ flag) {
    constexpr int MT = TM / 32;
    __shared__ __align__(16) bf16 As[TM*64];
    __shared__ __align__(16) bf16 Bs[128*64];
    const int z = blockIdx.z;
    A  += (size_t)z * zsA;
    Bt += (size_t)z * zsB;
    const size_t coff = (size_t)z * zsC;
    const int tid = threadIdx.x;
    const int wave = tid >> 6, lane = tid & 63;
    const int lrow = lane & 15, lq = lane >> 4;
    const size_t m0 = (size_t)blockIdx.y * TM;
    const int n0 = blockIdx.x * 128;
    const int wm = (wave >> 1) * (TM/2), wn = (wave & 1) * 64;
    const int ar = lane >> 3;
    const int gk = (lane & 7) ^ ar;
    f32x4 acc[MT][4] = {};

    for (int k0 = 0; k0 < K; k0 += 64) {
        if (k0) __syncthreads();
        #pragma unroll
        for (int i = 0; i < TM/32; i++) {
            int R = wave*(TM/4) + i*8;
            async_cp16(A + (m0 + R + ar)*lda + k0 + gk*8, As + R*64);
        }
        #pragma unroll
        for (int i = 0; i < 4; i++) {
            int R = wave*32 + i*8;
            async_cp16(Bt + (size_t)(n0 + R + ar)*K + k0 + gk*8, Bs + R*64);
        }
        __syncthreads();
        #pragma unroll
        for (int kk = 0; kk < 2; kk++) {
            bf16x8 af[MT], bfr[4];
            #pragma unroll
            for (int mt = 0; mt < MT; mt++) {
                int r = wm + mt*16 + lrow;
                int p = (kk*4 + lq) ^ (r & 7);
                af[mt] = *(const bf16x8*)(As + r*64 + p*8);
            }
            #pragma unroll
            for (int nt = 0; nt < 4; nt++) {
                int r = wn + nt*16 + lrow;
                int p = (kk*4 + lq) ^ (r & 7);
                bfr[nt] = *(const bf16x8*)(Bs + r*64 + p*8);
            }
            #pragma unroll
            for (int mt = 0; mt < MT; mt++)
                #pragma unroll
                for (int nt = 0; nt < 4; nt++)
                    acc[mt][nt] = __builtin_amdgcn_mfma_f32_16x16x32_bf16(af[mt], bfr[nt], acc[mt][nt], 0, 0, 0);
        }
    }

    const int isb = bias ? *flag : 0;
    #pragma unroll
    for (int mt = 0; mt < MT; mt++)
        #pragma unroll
        for (int nt = 0; nt < 4; nt++) {
            int col = n0 + wn + nt*16 + lrow;
            float bv = bias ? ldf(bias, boff + col, isb) : 0.0f;
            #pragma unroll
            for (int r = 0; r < 4; r++) {
                size_t row = m0 + wm + mt*16 + lq*4 + r;
                float x = acc[mt][nt][r] + bv;
                if (EPI == 0)      Cb[coff + row*N + col] = f2bf(x);
                else if (EPI == 1) Cb[coff + row*N + col] = f2bf(siluf(x));
                else               Cf[coff + row*N + col] += siluf(x);
            }
        }
}

// ---------------------------------------------------------------- fp8 MFMA GEMM, TM=64, N=512, BK=128 (k-permuted layout)
// LDS rows 128B (full bank wrap), 8x16B chunks, XOR q = c ^ (r&7), b128 reads = 2 fragments.
// EPI 3: e1-assemble, fp8 output with perm (feeds fp8 e2 GEMM). EPI 1: silu -> bf16.
template<int EPI>
__global__ __launch_bounds__(256) void gemm_fp8(
        const u8* __restrict__ A,
        const u8* __restrict__ Bt,
        int K,
        const float* __restrict__ cbias_l,
        const bf16* __restrict__ hnAB,
        const int* __restrict__ edat,
        u8* __restrict__ C8,
        const void* __restrict__ bias, size_t boff,
        bf16* __restrict__ Cb,
        const int* __restrict__ flag) {
    __shared__ __align__(16) u8 As[64*128];
    __shared__ __align__(16) u8 Bs[128*128];
    const int tid = threadIdx.x;
    const int wave = tid >> 6, lane = tid & 63;
    const int lrow = lane & 15, lq = lane >> 4;
    const size_t m0 = (size_t)blockIdx.y * 64;
    const int n0 = blockIdx.x * 128;
    const int wm = (wave >> 1) * 32, wn = (wave & 1) * 64;
    const int ar = lane >> 3;          // row in 8-row window
    const int gk = (lane & 7) ^ ar;    // global 16B chunk fetched
    f32x4 acc[2][4] = {};

    for (int k0 = 0; k0 < K; k0 += 128) {
        if (k0) __syncthreads();
        #pragma unroll
        for (int i = 0; i < 2; i++) {          // A: 8 windows of 8 rows, 2/wave
            int R = wave*16 + i*8;
            async_cp16(A + (size_t)(m0 + R + ar)*K + k0 + gk*16, As + R*128);
        }
        #pragma unroll
        for (int i = 0; i < 4; i++) {          // B: 16 windows, 4/wave
            int R = wave*32 + i*8;
            async_cp16(Bt + (size_t)(n0 + R + ar)*K + k0 + gk*16, Bs + R*128);
        }
        __syncthreads();
        #pragma unroll
        for (int kp = 0; kp < 2; kp++) {       // chunk-pair: 16B = 2 MFMA fragments
            i64x2 af[2], bfr[4];
            #pragma unroll
            for (int mt = 0; mt < 2; mt++) {
                int r = wm + mt*16 + lrow;
                int q = (lq*2 + kp) ^ (r & 7);
                af[mt] = *(const i64x2*)(As + r*128 + q*16);
            }
            #pragma unroll
            for (int nt = 0; nt < 4; nt++) {
                int r = wn + nt*16 + lrow;
                int q = (lq*2 + kp) ^ (r & 7);
                bfr[nt] = *(const i64x2*)(Bs + r*128 + q*16);
            }
            #pragma unroll
            for (int mt = 0; mt < 2; mt++)
                #pragma unroll
                for (int nt = 0; nt < 4; nt++) {
                    acc[mt][nt] = __builtin_amdgcn_mfma_f32_16x16x32_fp8_fp8(af[mt].x, bfr[nt].x, acc[mt][nt], 0, 0, 0);
                    acc[mt][nt] = __builtin_amdgcn_mfma_f32_16x16x32_fp8_fp8(af[mt].y, bfr[nt].y, acc[mt][nt], 0, 0, 0);
                }
        }
    }

    if constexpr (EPI == 3) {
        #pragma unroll
        for (int mt = 0; mt < 2; mt++) {
            #pragma unroll
            for (int r = 0; r < 4; r++) {
                size_t e = m0 + wm + mt*16 + lq*4 + r;
                const int4 q = *(const int4*)(edat + e*4);
                int se = q.x, de = q.y, g = q.z;
                #pragma unroll
                for (int nt = 0; nt < 4; nt++) {
                    int col = n0 + wn + nt*16 + lrow;
                    float x = acc[mt][nt][r]
                            + cbias_l[(size_t)g*512 + col]
                            + bf2f(hnAB[(size_t)se*1024 + col])
                            + bf2f(hnAB[(size_t)de*1024 + 512 + col]);
                    C8[e*512 + perm_k(col)] = f2f8(siluf(x));
                }
            }
        }
    } else {
        const int isb = *flag;
        #pragma unroll
        for (int mt = 0; mt < 2; mt++)
            #pragma unroll
            for (int nt = 0; nt < 4; nt++) {
                int col = n0 + wn + nt*16 + lrow;
                float bv = ldf(bias, boff + col, isb);
                #pragma unroll
                for (int r = 0; r < 4; r++) {
                    size_t row = m0 + wm + mt*16 + lq*4 + r;
                    Cb[row*512 + col] = f2bf(siluf(acc[mt][nt][r] + bv));
                }
            }
    }
}

// ---------------------------------------------------------------- agg: mean over each node's 19 contiguous edges
__global__ __launch_bounds__(256) void seg_mean(const bf16* __restrict__ e2,
                                                bf16* __restrict__ cat) {
    int n = blockIdx.x;
    #pragma unroll
    for (int jj = 0; jj < 2; jj++) {
        int j = threadIdx.x + jj*256;
        const bf16* base = e2 + (size_t)n*19*H_ + j;
        float s = 0.0f;
        #pragma unroll
        for (int i = 0; i < 19; i++) s += bf2f(base[(size_t)i*H_]);
        cat[(size_t)n*1024 + 512 + j] = f2bf(s / 19.0f);
    }
}

// ---------------------------------------------------------------- heads (hln lives in cat[:, :512], stride 1024)
__global__ __launch_bounds__(256) void pos_out(const bf16* __restrict__ hln,
                                               const void* __restrict__ W_coord,
                                               void* __restrict__ out,
                                               const int* __restrict__ flag) {
    int wave = threadIdx.x >> 6, lane = threadIdx.x & 63;
    int n = blockIdx.x*4 + wave;
    int isb = *flag;
    float s0 = 0, s1 = 0, s2 = 0;
    for (int k = lane; k < H_; k += 64) {
        float hv = bf2f(hln[(size_t)n*1024 + k]);
        s0 += hv * ldf(W_coord, k*3 + 0, isb);
        s1 += hv * ldf(W_coord, k*3 + 1, isb);
        s2 += hv * ldf(W_coord, k*3 + 2, isb);
    }
    for (int o = 32; o; o >>= 1) {
        s0 += __shfl_down(s0, o); s1 += __shfl_down(s1, o); s2 += __shfl_down(s2, o);
    }
    if (lane == 0) {
        if (isb) { bf16* o = (bf16*)out;  o[n*3] = f2bf(s0); o[n*3+1] = f2bf(s1); o[n*3+2] = f2bf(s2); }
        else     { float* o = (float*)out; o[n*3] = s0; o[n*3+1] = s1; o[n*3+2] = s2; }
    }
}

__global__ __launch_bounds__(512) void cell_out(const bf16* __restrict__ hln,
                                                const void* __restrict__ W_latout,
                                                const void* __restrict__ b_latout,
                                                const int* __restrict__ num_atoms,
                                                void* __restrict__ out,
                                                const int* __restrict__ flag) {
    __shared__ float red[8*6];
    int b = blockIdx.x, j = threadIdx.x;
    int isb = *flag;
    float s = 0.0f;
    for (int i = 0; i < NPG_; i++) s += bf2f(hln[(size_t)(b*NPG_ + i)*1024 + j]);
    float m = s / (float)num_atoms[b];
    float p[6];
    #pragma unroll
    for (int c = 0; c < 6; c++)
        p[c] = m * ldf(W_latout, j*6 + c, isb) + s * ldf(W_latout, (512 + j)*6 + c, isb);
    int w = j >> 6, lane = j & 63;
    #pragma unroll
    for (int c = 0; c < 6; c++) {
        float v = p[c];
        for (int o = 32; o; o >>= 1) v += __shfl_down(v, o);
        if (lane == 0) red[w*6 + c] = v;
    }
    __syncthreads();
    if (j < 6) {
        float v = 0.0f;
        for (int w2 = 0; w2 < 8; w2++) v += red[w2*6 + j];
        float r = v + ldf(b_latout, j, isb);
        if (isb) ((bf16*)out)[N_*3 + b*6 + j] = f2bf(r);
        else     ((float*)out)[N_*3 + b*6 + j] = r;
    }
}

// ================================================================ host
extern "C" void kernel_launch(void* const* d_in, const int* in_sizes, int n_in,
                              void* d_out, int out_size, void* d_ws, size_t ws_size,
                              hipStream_t stream) {
    const void* t          = d_in[0];
    const void* frac       = d_in[1];
    const void* latp       = d_in[2];
    const int*  atom_types = (const int*)d_in[3];
    const int*  num_atoms  = (const int*)d_in[4];
    const int*  node2graph = (const int*)d_in[5];
    const int*  edge_index = (const int*)d_in[6];
    const int*  e2g        = (const int*)d_in[7];
    const void* W_node     = d_in[8];
    const void* W_time     = d_in[9];
    const void* W_latent   = d_in[10];
    const void* ln_gamma   = d_in[11];
    const void* ln_beta    = d_in[12];
    const void* We1        = d_in[13];
    const void* be1        = d_in[14];
    const void* We2        = d_in[15];
    const void* be2        = d_in[16];
    const void* Wn1        = d_in[17];
    const void* bn1        = d_in[18];
    const void* Wn2        = d_in[19];
    const void* bn2        = d_in[20];
    const void* W_numatom  = d_in[21];
    const void* fln_gamma  = d_in[22];
    const void* fln_beta   = d_in[23];
    const void* W_coord    = d_in[24];
    const void* W_latout   = d_in[25];
    const void* b_latout   = d_in[26];

    auto AL = [](size_t b) { return (b + 255) & ~(size_t)255; };
    const size_t fixed =
        AL(4) + AL((size_t)B_*9*4) + AL((size_t)H_*4) + AL((size_t)N_*H_*4)
      + AL((size_t)E_*4*4) + AL((size_t)N_*1024*2) + AL((size_t)E_*KF8_)
      + AL((size_t)E_*512) + AL((size_t)E_*H_*2) + AL((size_t)N_*1024*2)
      + AL((size_t)N_*H_*2) + AL((size_t)7*128*512*2) + AL((size_t)NL_*B_*512*4);
    const size_t perlayer_w = AL((size_t)512*1024*2) + AL((size_t)512*KF8_)
                            + AL((size_t)512*512) + AL((size_t)512*1024*2) + AL((size_t)512*512*2);
    int allmode = (fixed + 6*perlayer_w <= ws_size) ? 1 : 0;
    size_t nw = allmode ? 6 : 1;

    char* p = (char*)d_ws;
    auto alloc = [&](size_t bytes) { char* r = p; p += (bytes + 255) & ~(size_t)255; return r; };
    int*   flag  = (int*)alloc(4);
    float* ltl   = (float*)alloc((size_t)B_*9*4);
    float* q     = (float*)alloc((size_t)H_*4);
    float* h     = (float*)alloc((size_t)N_*H_*4);
    int*   edat  = (int*)alloc((size_t)E_*4*4);
    bf16* hnAB  = (bf16*)alloc((size_t)N_*1024*2);
    u8*   femb8 = (u8*)alloc((size_t)E_*KF8_);
    u8*   e18   = (u8*)alloc((size_t)E_*512);       // prep alias: PQa (bf16 7*128*512)
    bf16* e2    = (bf16*)alloc((size_t)E_*H_*2);    // prep alias: PQbt
    bf16* cat   = (bf16*)alloc((size_t)N_*1024*2);
    bf16* n1s   = (bf16*)alloc((size_t)N_*H_*2);
    bf16* PQc   = (bf16*)alloc((size_t)7*128*512*2);
    float* cbias = (float*)alloc((size_t)NL_*B_*512*4);
    bf16* WtAB  = (bf16*)alloc(nw*(size_t)512*1024*2);
    u8*   Wtf8  = (u8*)alloc(nw*(size_t)512*KF8_);
    u8*   Wte28 = (u8*)alloc(nw*(size_t)512*512);
    bf16* Wtn1  = (bf16*)alloc(nw*(size_t)512*1024*2);
    bf16* Wtn2  = (bf16*)alloc(nw*(size_t)512*512*2);
    bf16* PQa   = (bf16*)e18;
    bf16* PQbt  = e2;

    if ((size_t)(p - (char*)d_ws) > ws_size) {
        ws_sentinel<<<1, 64, 0, stream>>>((bf16*)d_out);
        return;
    }

    // ---- prep
    detect_dtype<<<1, 64, 0, stream>>>((const unsigned int*)t, flag);
    prep_graph<<<1, 64, 0, stream>>>(latp, ltl, flag);
    prep_q<<<1, 512, 0, stream>>>(W_time, W_latent, q, flag);
    pq_gather<<<dim3(7, 16), 256, 0, stream>>>(W_node, W_numatom, PQa, flag);
    transpose_pq<<<dim3(16, 16, 7), dim3(32, 8), 0, stream>>>(W_latent, We1, PQbt, flag);
    gemm_bt<0,128><<<dim3(4, 1, 7), 256, 0, stream>>>(
        PQa, 512, PQbt, nullptr, 0, PQc, nullptr, 512, 512,
        (size_t)128*512, (size_t)512*512, (size_t)128*512, flag);
    cbias_prep<<<dim3(NL_, B_), 512, 0, stream>>>(PQc, be1, num_atoms, cbias, flag);
    node_embed_fast<<<N_, 512, 0, stream>>>(PQc, q, t, atom_types, node2graph, h, flag);
    edge_prep<<<E_, 384, 0, stream>>>(frac, edge_index, e2g, latp, ltl, edat, femb8, flag);

    if (allmode) {
        transpose_layer<<<dim3(16, 32, 36), dim3(32, 8), 0, stream>>>(
            We1, We2, Wn1, Wn2, 0, 1, WtAB, Wtf8, Wte28, Wtn1, Wtn2, flag);
        wtf_tail<<<6, 512, 0, stream>>>(We1, 0, 1, Wtf8, flag);
    }

    // ---- layers
    for (size_t l = 0; l < NL_; l++) {
        size_t lw = allmode ? l : 0;
        bf16* WtABl = WtAB + lw*512*1024;
        u8*   Wtf8l = Wtf8 + lw*(size_t)512*KF8_;
        u8*   Wte28l = Wte28 + lw*(size_t)512*512;
        bf16* Wtn1l = Wtn1 + lw*512*1024;
        bf16* Wtn2l = Wtn2 + lw*512*512;
        if (!allmode) {
            transpose_layer<<<dim3(16, 32, 6), dim3(32, 8), 0, stream>>>(
                We1, We2, Wn1, Wn2, l, 0, WtAB, Wtf8, Wte28, Wtn1, Wtn2, flag);
            wtf_tail<<<1, 512, 0, stream>>>(We1, l, 0, Wtf8, flag);
        }
        ln_kernel<<<N_, 256, 0, stream>>>(h, ln_gamma, ln_beta, l*H_, cat, flag);
        // hnAB = hn @ [WA|WB]
        gemm_bt<0,64><<<dim3(8, N_/64), 256, 0, stream>>>(
            cat, 1024, WtABl, nullptr, 0, hnAB, nullptr, 512, 1024, 0, 0, 0, flag);
        // e18 = fp8(silu(femb8 @ Wtf8 + cbias[g] + hnA[src] + hnB[dst]))
        gemm_fp8<3><<<dim3(4, E_/64), 256, 0, stream>>>(
            femb8, Wtf8l, KF8_, cbias + l*B_*512, hnAB, edat, e18, nullptr, 0, nullptr, flag);
        // e2 = silu(e18 @ Wte28 + be2)   [fp8 MFMA]
        gemm_fp8<1><<<dim3(4, E_/64), 256, 0, stream>>>(
            e18, Wte28l, 512, nullptr, nullptr, nullptr, nullptr, be2, l*H_, e2, flag);
        seg_mean<<<N_, 256, 0, stream>>>(e2, cat);
        // n1s = silu(cat@Wn1 + bn1)
        gemm_bt<1,64><<<dim3(4, N_/64), 256, 0, stream>>>(
            cat, 1024, Wtn1l, bn1, l*H_, n1s, nullptr, 1024, 512, 0, 0, 0, flag);
        // h += silu(n1s@Wn2 + bn2)
        gemm_bt<2,64><<<dim3(4, N_/64), 256, 0, stream>>>(
            n1s, 512, Wtn2l, bn2, l*H_, nullptr, h, 512, 512, 0, 0, 0, flag);
    }

    // ---- heads
    ln_kernel<<<N_, 256, 0, stream>>>(h, fln_gamma, fln_beta, 0, cat, flag);
    pos_out<<<N_/4, 256, 0, stream>>>(cat, W_coord, d_out, flag);
    cell_out<<<B_, 512, 0, stream>>>(cat, W_latout, b_latout, num_atoms, d_out, flag);
}